// Round 1
// baseline (215.878 us; speedup 1.0000x reference)
//
#include <hip/hip_runtime.h>
#include <math.h>

#define B_N    8192
#define D_DIM  192
#define C_CLS  1024
#define MARGIN 0.2f
#define EPS_T  1e-6f

#define TI     64
#define TJ     128
#define JSPLIT 16
#define JLEN   (B_N / JSPLIT)   // 512
#define LDB    200              // LDS row stride in bf16 (400 B: 16B-aligned, good bank spread)

typedef short v8s  __attribute__((ext_vector_type(8)));
typedef float v16f __attribute__((ext_vector_type(16)));

__device__ __forceinline__ unsigned fkey(float f) {
  unsigned u = __float_as_uint(f);
  return (u & 0x80000000u) ? ~u : (u | 0x80000000u);
}

__device__ __forceinline__ unsigned short to_bf(float x) {
  unsigned u = __float_as_uint(x);
  u += 0x7fffu + ((u >> 16) & 1u);
  return (unsigned short)(u >> 16);
}

// ---------------- prep: cvt fp32->bf16, sq = ||e||^2, init ws ----------------
__global__ __launch_bounds__(256) void prep_kernel(
    const float* __restrict__ e, unsigned short* __restrict__ ebf,
    float* __restrict__ sq,
    unsigned long long* __restrict__ posw, unsigned long long* __restrict__ negw,
    float* __restrict__ accum) {
  int w = threadIdx.x >> 6, lane = threadIdx.x & 63;
  int row = blockIdx.x * 4 + w;
  const float* p = e + (size_t)row * D_DIM;
  float v0 = p[lane], v1 = p[lane + 64], v2 = p[lane + 128];
  unsigned short* q = ebf + (size_t)row * D_DIM;
  q[lane] = to_bf(v0); q[lane + 64] = to_bf(v1); q[lane + 128] = to_bf(v2);
  float s = v0 * v0 + v1 * v1 + v2 * v2;
  #pragma unroll
  for (int off = 32; off; off >>= 1) s += __shfl_xor(s, off);
  if (lane == 0) sq[row] = s;
  int b = blockIdx.x;
  if (b < 32)       posw[b * 256 + threadIdx.x] = 0ULL;
  else if (b < 64)  negw[(b - 32) * 256 + threadIdx.x] = ~0ULL;
  else if (b == 64 && threadIdx.x < 4) ((unsigned*)accum)[threadIdx.x] = 0u;
}

// ---------------- hard mining (j=M from LDS, i=N in regs) + fused CE ----------------
// wave w owns j-band [w*32, w*32+32) of each TJ=128 tile, and all TI=64 i-cols.
__global__ __launch_bounds__(256, 3) void mine_kernel(
    const unsigned short* __restrict__ ebf, const int* __restrict__ tgt,
    const float* __restrict__ sq, const float* __restrict__ logits,
    unsigned long long* __restrict__ posw, unsigned long long* __restrict__ negw,
    float* __restrict__ accum) {
  __shared__ unsigned short lds_b[TJ * LDB];   // 51200 B
  __shared__ int   lds_t[TJ];
  __shared__ float lds_s[TJ];
  __shared__ unsigned long long pmrg[TI];
  __shared__ unsigned long long nmrg[TI];
  __shared__ float ce_part[4];

  const int tid  = threadIdx.x;
  const int w    = tid >> 6;      // wave id = j band within tile
  const int lane = tid & 63;
  const int n5   = lane & 31;
  const int h    = lane >> 5;
  const int i0 = blockIdx.x * TI;
  const int jb = blockIdx.y * JLEN;

  if (tid < TI) { pmrg[tid] = 0ULL; nmrg[tid] = ~0ULL; }

  // ---- stage this block's 64 i-rows through LDS (coalesced), pull B-frags to regs ----
  {
    const unsigned short* src = ebf + (size_t)i0 * D_DIM;
    #pragma unroll
    for (int t = 0; t < 6; ++t) {           // 64 rows * 24 chunks = 1536 = 6*256
      int c = t * 256 + tid;
      int row = c / 24;
      int off = c - row * 24;
      *(v8s*)&lds_b[row * LDB + off * 8] = *(const v8s*)(src + (size_t)row * D_DIM + off * 8);
    }
  }
  __syncthreads();
  v8s bfrag[2][12];
  #pragma unroll
  for (int tb = 0; tb < 2; ++tb)
    #pragma unroll
    for (int kc = 0; kc < 12; ++kc)
      bfrag[tb][kc] = *(const v8s*)&lds_b[(tb * 32 + n5) * LDB + kc * 16 + h * 8];

  int my_t[2];
  #pragma unroll
  for (int tb = 0; tb < 2; ++tb) my_t[tb] = tgt[i0 + tb * 32 + n5];

  float    pv[2] = {-3.4e38f, -3.4e38f}, nv[2] = {3.4e38f, 3.4e38f};
  unsigned pi_[2] = {0u, 0u}, ni_[2] = {0xFFFFFFFFu, 0xFFFFFFFFu};

  for (int j0 = jb; j0 < jb + JLEN; j0 += TJ) {
    __syncthreads();
    // stage j-rows (M side)
    #pragma unroll
    for (int t = 0; t < 12; ++t) {
      int c = t * 256 + tid;
      int row = c / 24;
      int off = c - row * 24;
      *(v8s*)&lds_b[row * LDB + off * 8] =
          *(const v8s*)(ebf + (size_t)(j0 + row) * D_DIM + off * 8);
    }
    if (tid < TJ) { lds_t[tid] = tgt[j0 + tid]; lds_s[tid] = sq[j0 + tid]; }
    __syncthreads();

    v16f acc[2];
    #pragma unroll
    for (int tb = 0; tb < 2; ++tb)
      #pragma unroll
      for (int r = 0; r < 16; ++r) acc[tb][r] = 0.f;

    #pragma unroll
    for (int kc = 0; kc < 12; ++kc) {
      v8s afr = *(const v8s*)&lds_b[(w * 32 + n5) * LDB + kc * 16 + h * 8];
      acc[0] = __builtin_amdgcn_mfma_f32_32x32x16_bf16(afr, bfrag[0][kc], acc[0], 0, 0, 0);
      acc[1] = __builtin_amdgcn_mfma_f32_32x32x16_bf16(afr, bfrag[1][kc], acc[1], 0, 0, 0);
    }

    // epilogue: rows decode as j = w*32 + q + 8p + 4h ; col = i = tb*32 + (lane&31)
    #pragma unroll
    for (int p = 0; p < 4; ++p) {
      int jb4 = w * 32 + p * 8 + h * 4;
      float4 s4 = *(const float4*)&lds_s[jb4];   // broadcast (2 uniq addrs/wave)
      int4   t4 = *(const int4*)&lds_t[jb4];
      #pragma unroll
      for (int q = 0; q < 4; ++q) {
        float sv = (q == 0) ? s4.x : (q == 1) ? s4.y : (q == 2) ? s4.z : s4.w;
        int   tv = (q == 0) ? t4.x : (q == 1) ? t4.y : (q == 2) ? t4.z : t4.w;
        unsigned jg = (unsigned)(j0 + jb4 + q);
        #pragma unroll
        for (int tb = 0; tb < 2; ++tb) {
          float val = fmaf(acc[tb][p * 4 + q], -2.0f, sv);
          bool same = (tv == my_t[tb]);
          float vp = same ? val : -3.4e38f;
          float vn = same ? 3.4e38f : val;
          if (vp > pv[tb]) { pv[tb] = vp; pi_[tb] = jg; }
          if (vn < nv[tb]) { nv[tb] = vn; ni_[tb] = jg; }
        }
      }
    }
  }

  // ---- merge: h-partner lanes (shfl), then 4 waves via LDS atomics, then global ----
  #pragma unroll
  for (int tb = 0; tb < 2; ++tb) {
    unsigned long long pk =
        ((unsigned long long)fkey(pv[tb]) << 32) | (unsigned long long)(unsigned)(~pi_[tb]);
    unsigned long long nk =
        ((unsigned long long)fkey(nv[tb]) << 32) | (unsigned long long)ni_[tb];
    unsigned long long po = __shfl_xor(pk, 32);
    unsigned long long no = __shfl_xor(nk, 32);
    pk = pk > po ? pk : po;
    nk = nk < no ? nk : no;
    if (h == 0) {
      atomicMax(&pmrg[tb * 32 + n5], pk);
      atomicMin(&nmrg[tb * 32 + n5], nk);
    }
  }
  __syncthreads();
  if (tid < TI) {
    atomicMax(&posw[i0 + tid], pmrg[tid]);
    atomicMin(&negw[i0 + tid], nmrg[tid]);
  }

  // ---- fused cross-entropy: this block handles 4 logits rows (1 per wave) ----
  {
    int row = (blockIdx.y * 128 + blockIdx.x) * 4 + w;
    const float* lp = logits + (size_t)row * C_CLS;
    float4 x[4];
    #pragma unroll
    for (int t = 0; t < 4; ++t) x[t] = *(const float4*)(lp + lane * 4 + 256 * t);
    float m = -3.4e38f;
    #pragma unroll
    for (int t = 0; t < 4; ++t)
      m = fmaxf(m, fmaxf(fmaxf(x[t].x, x[t].y), fmaxf(x[t].z, x[t].w)));
    #pragma unroll
    for (int off = 32; off; off >>= 1) m = fmaxf(m, __shfl_xor(m, off));
    float s = 0.f;
    #pragma unroll
    for (int t = 0; t < 4; ++t)
      s += __expf(x[t].x - m) + __expf(x[t].y - m) +
           __expf(x[t].z - m) + __expf(x[t].w - m);
    #pragma unroll
    for (int off = 32; off; off >>= 1) s += __shfl_xor(s, off);
    if (lane == 0) ce_part[w] = m + __logf(s) - lp[tgt[row]];
  }
  __syncthreads();
  if (tid == 0)
    atomicAdd(&accum[0], ce_part[0] + ce_part[1] + ce_part[2] + ce_part[3]);
}

// ---------------- triplet loss on mined indices + last-block finalize ----------------
__global__ __launch_bounds__(1024) void trip_fin_kernel(
    const float* __restrict__ e,
    const unsigned long long* __restrict__ posw,
    const unsigned long long* __restrict__ negw,
    float* __restrict__ accum, float* __restrict__ out) {
  __shared__ float ssum[16];
  __shared__ float scnt[16];
  int w = threadIdx.x >> 6, lane = threadIdx.x & 63;
  int i = blockIdx.x * 16 + w;
  unsigned long long pp = posw[i], np = negw[i];
  unsigned pidx = ~(unsigned)pp;
  unsigned nidx = (unsigned)np;
  float res = 0.f, c = 0.f;
  // pidx == i means self won the argmax => no real positive => invalid row
  if (pp != 0ULL && np != ~0ULL && pidx != (unsigned)i) {
    const float* pa = e + (size_t)i * D_DIM;
    const float* pb = e + (size_t)pidx * D_DIM;
    const float* pc = e + (size_t)nidx * D_DIM;
    float dap = 0.f, dan = 0.f;
    #pragma unroll
    for (int t = 0; t < 3; ++t) {
      int k = lane + 64 * t;
      float av = pa[k];
      float d1 = av - pb[k] + EPS_T;
      float d2 = av - pc[k] + EPS_T;
      dap += d1 * d1;
      dan += d2 * d2;
    }
    #pragma unroll
    for (int off = 32; off; off >>= 1) {
      dap += __shfl_xor(dap, off);
      dan += __shfl_xor(dan, off);
    }
    res = fmaxf(sqrtf(dap) - sqrtf(dan) + MARGIN, 0.f);
    c = 1.f;
  }
  if (lane == 0) { ssum[w] = res; scnt[w] = c; }
  __syncthreads();
  if (threadIdx.x == 0) {
    float a = 0.f, b = 0.f;
    #pragma unroll
    for (int k = 0; k < 16; ++k) { a += ssum[k]; b += scnt[k]; }
    atomicAdd(&accum[1], a);
    atomicAdd(&accum[2], b);
    __threadfence();
    unsigned old = atomicAdd((unsigned*)&accum[3], 1u);
    if (old == 511u) {
      __threadfence();
      float cls = atomicAdd(&accum[0], 0.f);   // coherent reads via atomics
      float ts  = atomicAdd(&accum[1], 0.f);
      float tc  = atomicAdd(&accum[2], 0.f);
      float trip = (tc > 0.f) ? ts / fmaxf(tc, 1.f) : 0.f;
      out[0] = cls / (float)B_N + trip;
    }
  }
}

extern "C" void kernel_launch(void* const* d_in, const int* in_sizes, int n_in,
                              void* d_out, int out_size, void* d_ws, size_t ws_size,
                              hipStream_t stream) {
  const float* emb    = (const float*)d_in[0];
  const float* logits = (const float*)d_in[1];
  const int*   tgt    = (const int*)d_in[2];
  float* out = (float*)d_out;

  char* ws = (char*)d_ws;
  unsigned short* ebf = (unsigned short*)ws;                          // 3,145,728 B
  unsigned long long* posw = (unsigned long long*)(ws + 3145728);     // 65536 B
  unsigned long long* negw = (unsigned long long*)(ws + 3145728 + 65536);
  float* sq    = (float*)(ws + 3145728 + 131072);                     // 32768 B
  float* accum = (float*)(ws + 3145728 + 163840);                     // 16 B: cls,tsum,tcnt,counter

  prep_kernel<<<2048, 256, 0, stream>>>(emb, ebf, sq, posw, negw, accum);
  mine_kernel<<<dim3(B_N / TI, JSPLIT), 256, 0, stream>>>(ebf, tgt, sq, logits, posw, negw, accum);
  trip_fin_kernel<<<512, 1024, 0, stream>>>(emb, posw, negw, accum, out);
}

// Round 2
// 192.456 us; speedup vs baseline: 1.1217x; 1.1217x over previous
//
#include <hip/hip_runtime.h>
#include <math.h>

#define B_N    8192
#define D_DIM  192
#define C_CLS  1024
#define MARGIN 0.2f
#define EPS_T  1e-6f

#define TI     64
#define TJ     128
#define JSPLIT 16
#define JLEN   (B_N / JSPLIT)   // 512
#define RB     384              // bytes per LDS row (linear 192 bf16, required by global_load_lds)

typedef short v8s  __attribute__((ext_vector_type(8)));
typedef float v16f __attribute__((ext_vector_type(16)));

typedef __attribute__((address_space(3))) unsigned int       lds_u32;
typedef __attribute__((address_space(1))) const unsigned int glb_u32;

__device__ __forceinline__ void gll16(const void* g, void* l) {
  __builtin_amdgcn_global_load_lds((glb_u32*)g, (lds_u32*)l, 16, 0, 0);
}

// XOR swizzle: physical byte for logical (row r, col-byte cb). Bijective involution
// within each 384-B row; 16B-aligned cb stays 16B-aligned.
__device__ __forceinline__ int swzb(int r, int cb) {
  return r * RB + (cb ^ ((r & 7) << 4));
}

__device__ __forceinline__ unsigned fkey(float f) {
  unsigned u = __float_as_uint(f);
  return (u & 0x80000000u) ? ~u : (u | 0x80000000u);
}

__device__ __forceinline__ unsigned short to_bf(float x) {
  unsigned u = __float_as_uint(x);
  u += 0x7fffu + ((u >> 16) & 1u);
  return (unsigned short)(u >> 16);
}

// ---------------- prep: cvt fp32->bf16, sq = ||e||^2, init ws ----------------
__global__ __launch_bounds__(256) void prep_kernel(
    const float* __restrict__ e, unsigned short* __restrict__ ebf,
    float* __restrict__ sq,
    unsigned long long* __restrict__ posw, unsigned long long* __restrict__ negw,
    float* __restrict__ accum) {
  int w = threadIdx.x >> 6, lane = threadIdx.x & 63;
  int row = blockIdx.x * 4 + w;
  const float* p = e + (size_t)row * D_DIM;
  float v0 = p[lane], v1 = p[lane + 64], v2 = p[lane + 128];
  unsigned short* q = ebf + (size_t)row * D_DIM;
  q[lane] = to_bf(v0); q[lane + 64] = to_bf(v1); q[lane + 128] = to_bf(v2);
  float s = v0 * v0 + v1 * v1 + v2 * v2;
  #pragma unroll
  for (int off = 32; off; off >>= 1) s += __shfl_xor(s, off);
  if (lane == 0) sq[row] = s;
  int b = blockIdx.x;
  if (b < 32)       posw[b * 256 + threadIdx.x] = 0ULL;
  else if (b < 64)  negw[(b - 32) * 256 + threadIdx.x] = ~0ULL;
  else if (b == 64 && threadIdx.x < 4) ((unsigned*)accum)[threadIdx.x] = 0u;
}

// ---------------- hard mining (j=M from LDS, i=N in regs) + fused CE ----------------
// wave w owns j-band [w*32, w*32+32) of each TJ=128 tile, and all TI=64 i-cols.
// Staging: global_load_lds (linear LDS dest) with inverse-swizzled global source;
// fragment ds_reads apply the same XOR swizzle.
__global__ __launch_bounds__(256, 3) void mine_kernel(
    const unsigned short* __restrict__ ebf, const int* __restrict__ tgt,
    const float* __restrict__ sq, const float* __restrict__ logits,
    unsigned long long* __restrict__ posw, unsigned long long* __restrict__ negw,
    float* __restrict__ accum) {
  __shared__ unsigned short lds_b[TJ * (RB / 2)];   // 49152 B, linear rows of 384 B
  __shared__ int   lds_t[TJ];
  __shared__ float lds_s[TJ];
  __shared__ unsigned long long pmrg[TI];
  __shared__ unsigned long long nmrg[TI];
  __shared__ float ce_part[4];

  const int tid  = threadIdx.x;
  const int w    = tid >> 6;      // wave id = j band within tile
  const int lane = tid & 63;
  const int n5   = lane & 31;
  const int h    = lane >> 5;
  const int i0 = blockIdx.x * TI;
  const int jb = blockIdx.y * JLEN;

  char* ldsc = (char*)lds_b;

  if (tid < TI) { pmrg[tid] = 0ULL; nmrg[tid] = ~0ULL; }

  // ---- stage this block's 64 i-rows: async HBM->LDS, swizzled source ----
  {
    const char* src = (const char*)(ebf + (size_t)i0 * D_DIM);
    #pragma unroll
    for (int t = 0; t < 6; ++t) {           // 64 rows * 24 chunks = 1536 = 6*256
      int c  = t * 256 + tid;
      int r  = c / 24;
      int cb = (c - r * 24) * 16;
      gll16(src + r * RB + (cb ^ ((r & 7) << 4)),
            ldsc + (t * 256 + (tid & ~63)) * 16);
    }
  }
  __syncthreads();
  v8s bfrag[2][12];
  #pragma unroll
  for (int tb = 0; tb < 2; ++tb)
    #pragma unroll
    for (int kc = 0; kc < 12; ++kc)
      bfrag[tb][kc] = *(const v8s*)(ldsc + swzb(tb * 32 + n5, kc * 32 + h * 16));

  int my_t[2];
  #pragma unroll
  for (int tb = 0; tb < 2; ++tb) my_t[tb] = tgt[i0 + tb * 32 + n5];

  float    pv[2] = {-3.4e38f, -3.4e38f}, nv[2] = {3.4e38f, 3.4e38f};
  unsigned pi_[2] = {0u, 0u}, ni_[2] = {0xFFFFFFFFu, 0xFFFFFFFFu};

  for (int j0 = jb; j0 < jb + JLEN; j0 += TJ) {
    __syncthreads();
    // stage j-rows (M side): async HBM->LDS, swizzled source
    {
      const char* src = (const char*)(ebf + (size_t)j0 * D_DIM);
      #pragma unroll
      for (int t = 0; t < 12; ++t) {        // 128 rows * 24 chunks = 3072 = 12*256
        int c  = t * 256 + tid;
        int r  = c / 24;
        int cb = (c - r * 24) * 16;
        gll16(src + r * RB + (cb ^ ((r & 7) << 4)),
              ldsc + (t * 256 + (tid & ~63)) * 16);
      }
    }
    if (tid < TJ) { lds_t[tid] = tgt[j0 + tid]; lds_s[tid] = sq[j0 + tid]; }
    __syncthreads();   // drains vmcnt: all LDS writes landed

    v16f acc[2];
    #pragma unroll
    for (int tb = 0; tb < 2; ++tb)
      #pragma unroll
      for (int r = 0; r < 16; ++r) acc[tb][r] = 0.f;

    #pragma unroll
    for (int kc = 0; kc < 12; ++kc) {
      v8s afr = *(const v8s*)(ldsc + swzb(w * 32 + n5, kc * 32 + h * 16));
      acc[0] = __builtin_amdgcn_mfma_f32_32x32x16_bf16(afr, bfrag[0][kc], acc[0], 0, 0, 0);
      acc[1] = __builtin_amdgcn_mfma_f32_32x32x16_bf16(afr, bfrag[1][kc], acc[1], 0, 0, 0);
    }

    // epilogue: rows decode as j = w*32 + q + 8p + 4h ; col = i = tb*32 + (lane&31)
    #pragma unroll
    for (int p = 0; p < 4; ++p) {
      int jb4 = w * 32 + p * 8 + h * 4;
      float4 s4 = *(const float4*)&lds_s[jb4];   // broadcast (2 uniq addrs/wave)
      int4   t4 = *(const int4*)&lds_t[jb4];
      #pragma unroll
      for (int q = 0; q < 4; ++q) {
        float sv = (q == 0) ? s4.x : (q == 1) ? s4.y : (q == 2) ? s4.z : s4.w;
        int   tv = (q == 0) ? t4.x : (q == 1) ? t4.y : (q == 2) ? t4.z : t4.w;
        unsigned jg = (unsigned)(j0 + jb4 + q);
        #pragma unroll
        for (int tb = 0; tb < 2; ++tb) {
          float val = fmaf(acc[tb][p * 4 + q], -2.0f, sv);
          bool same = (tv == my_t[tb]);
          float vp = same ? val : -3.4e38f;
          float vn = same ? 3.4e38f : val;
          if (vp > pv[tb]) { pv[tb] = vp; pi_[tb] = jg; }
          if (vn < nv[tb]) { nv[tb] = vn; ni_[tb] = jg; }
        }
      }
    }
  }

  // ---- merge: h-partner lanes (shfl), then 4 waves via LDS atomics, then global ----
  #pragma unroll
  for (int tb = 0; tb < 2; ++tb) {
    unsigned long long pk =
        ((unsigned long long)fkey(pv[tb]) << 32) | (unsigned long long)(unsigned)(~pi_[tb]);
    unsigned long long nk =
        ((unsigned long long)fkey(nv[tb]) << 32) | (unsigned long long)ni_[tb];
    unsigned long long po = __shfl_xor(pk, 32);
    unsigned long long no = __shfl_xor(nk, 32);
    pk = pk > po ? pk : po;
    nk = nk < no ? nk : no;
    if (h == 0) {
      atomicMax(&pmrg[tb * 32 + n5], pk);
      atomicMin(&nmrg[tb * 32 + n5], nk);
    }
  }
  __syncthreads();
  if (tid < TI) {
    atomicMax(&posw[i0 + tid], pmrg[tid]);
    atomicMin(&negw[i0 + tid], nmrg[tid]);
  }

  // ---- fused cross-entropy: this block handles 4 logits rows (1 per wave) ----
  {
    int row = (blockIdx.y * 128 + blockIdx.x) * 4 + w;
    const float* lp = logits + (size_t)row * C_CLS;
    float4 x[4];
    #pragma unroll
    for (int t = 0; t < 4; ++t) x[t] = *(const float4*)(lp + lane * 4 + 256 * t);
    float m = -3.4e38f;
    #pragma unroll
    for (int t = 0; t < 4; ++t)
      m = fmaxf(m, fmaxf(fmaxf(x[t].x, x[t].y), fmaxf(x[t].z, x[t].w)));
    #pragma unroll
    for (int off = 32; off; off >>= 1) m = fmaxf(m, __shfl_xor(m, off));
    float s = 0.f;
    #pragma unroll
    for (int t = 0; t < 4; ++t)
      s += __expf(x[t].x - m) + __expf(x[t].y - m) +
           __expf(x[t].z - m) + __expf(x[t].w - m);
    #pragma unroll
    for (int off = 32; off; off >>= 1) s += __shfl_xor(s, off);
    if (lane == 0) ce_part[w] = m + __logf(s) - lp[tgt[row]];
  }
  __syncthreads();
  if (tid == 0)
    atomicAdd(&accum[0], ce_part[0] + ce_part[1] + ce_part[2] + ce_part[3]);
}

// ---------------- triplet loss on mined indices + last-block finalize ----------------
__global__ __launch_bounds__(1024) void trip_fin_kernel(
    const float* __restrict__ e,
    const unsigned long long* __restrict__ posw,
    const unsigned long long* __restrict__ negw,
    float* __restrict__ accum, float* __restrict__ out) {
  __shared__ float ssum[16];
  __shared__ float scnt[16];
  int w = threadIdx.x >> 6, lane = threadIdx.x & 63;
  int i = blockIdx.x * 16 + w;
  unsigned long long pp = posw[i], np = negw[i];
  unsigned pidx = ~(unsigned)pp;
  unsigned nidx = (unsigned)np;
  float res = 0.f, c = 0.f;
  // pidx == i means self won the argmax => no real positive => invalid row
  if (pp != 0ULL && np != ~0ULL && pidx != (unsigned)i) {
    const float* pa = e + (size_t)i * D_DIM;
    const float* pb = e + (size_t)pidx * D_DIM;
    const float* pc = e + (size_t)nidx * D_DIM;
    float dap = 0.f, dan = 0.f;
    #pragma unroll
    for (int t = 0; t < 3; ++t) {
      int k = lane + 64 * t;
      float av = pa[k];
      float d1 = av - pb[k] + EPS_T;
      float d2 = av - pc[k] + EPS_T;
      dap += d1 * d1;
      dan += d2 * d2;
    }
    #pragma unroll
    for (int off = 32; off; off >>= 1) {
      dap += __shfl_xor(dap, off);
      dan += __shfl_xor(dan, off);
    }
    res = fmaxf(sqrtf(dap) - sqrtf(dan) + MARGIN, 0.f);
    c = 1.f;
  }
  if (lane == 0) { ssum[w] = res; scnt[w] = c; }
  __syncthreads();
  if (threadIdx.x == 0) {
    float a = 0.f, b = 0.f;
    #pragma unroll
    for (int k = 0; k < 16; ++k) { a += ssum[k]; b += scnt[k]; }
    atomicAdd(&accum[1], a);
    atomicAdd(&accum[2], b);
    __threadfence();
    unsigned old = atomicAdd((unsigned*)&accum[3], 1u);
    if (old == 511u) {
      __threadfence();
      float cls = atomicAdd(&accum[0], 0.f);   // coherent reads via atomics
      float ts  = atomicAdd(&accum[1], 0.f);
      float tc  = atomicAdd(&accum[2], 0.f);
      float trip = (tc > 0.f) ? ts / fmaxf(tc, 1.f) : 0.f;
      out[0] = cls / (float)B_N + trip;
    }
  }
}

extern "C" void kernel_launch(void* const* d_in, const int* in_sizes, int n_in,
                              void* d_out, int out_size, void* d_ws, size_t ws_size,
                              hipStream_t stream) {
  const float* emb    = (const float*)d_in[0];
  const float* logits = (const float*)d_in[1];
  const int*   tgt    = (const int*)d_in[2];
  float* out = (float*)d_out;

  char* ws = (char*)d_ws;
  unsigned short* ebf = (unsigned short*)ws;                          // 3,145,728 B
  unsigned long long* posw = (unsigned long long*)(ws + 3145728);     // 65536 B
  unsigned long long* negw = (unsigned long long*)(ws + 3145728 + 65536);
  float* sq    = (float*)(ws + 3145728 + 131072);                     // 32768 B
  float* accum = (float*)(ws + 3145728 + 163840);                     // 16 B: cls,tsum,tcnt,counter

  prep_kernel<<<2048, 256, 0, stream>>>(emb, ebf, sq, posw, negw, accum);
  mine_kernel<<<dim3(B_N / TI, JSPLIT), 256, 0, stream>>>(ebf, tgt, sq, logits, posw, negw, accum);
  trip_fin_kernel<<<512, 1024, 0, stream>>>(emb, posw, negw, accum, out);
}

// Round 4
// 159.254 us; speedup vs baseline: 1.3556x; 1.2085x over previous
//
#include <hip/hip_runtime.h>
#include <math.h>

#define B_N    8192
#define D_DIM  192
#define C_CLS  1024
#define MARGIN 0.2f
#define EPS_T  1e-6f

#define TI     64
#define TJ     128
#define JSPLIT 16
#define JLEN   (B_N / JSPLIT)   // 512
#define RB     384              // bytes per LDS row (linear 192 bf16, required by global_load_lds)

typedef short v8s  __attribute__((ext_vector_type(8)));
typedef float v16f __attribute__((ext_vector_type(16)));

typedef __attribute__((address_space(3))) unsigned int       lds_u32;
typedef __attribute__((address_space(1))) const unsigned int glb_u32;

__device__ __forceinline__ void gll16(const void* g, void* l) {
  __builtin_amdgcn_global_load_lds((glb_u32*)g, (lds_u32*)l, 16, 0, 0);
}

// XOR swizzle: physical byte for logical (row r, col-byte cb). Bijective involution
// within each 384-B row; 16B-aligned cb stays 16B-aligned.
__device__ __forceinline__ int swzb(int r, int cb) {
  return r * RB + (cb ^ ((r & 7) << 4));
}

__device__ __forceinline__ unsigned fkey(float f) {
  unsigned u = __float_as_uint(f);
  return (u & 0x80000000u) ? ~u : (u | 0x80000000u);
}

__device__ __forceinline__ unsigned short to_bf(float x) {
  unsigned u = __float_as_uint(x);
  u += 0x7fffu + ((u >> 16) & 1u);
  return (unsigned short)(u >> 16);
}

// ---------------- prep: cvt fp32->bf16, sq = ||e||^2, init ws ----------------
__global__ __launch_bounds__(256) void prep_kernel(
    const float* __restrict__ e, unsigned short* __restrict__ ebf,
    float* __restrict__ sq,
    unsigned long long* __restrict__ posw, unsigned long long* __restrict__ negw,
    float* __restrict__ accum) {
  int w = threadIdx.x >> 6, lane = threadIdx.x & 63;
  int row = blockIdx.x * 4 + w;
  const float* p = e + (size_t)row * D_DIM;
  float v0 = p[lane], v1 = p[lane + 64], v2 = p[lane + 128];
  unsigned short* q = ebf + (size_t)row * D_DIM;
  q[lane] = to_bf(v0); q[lane + 64] = to_bf(v1); q[lane + 128] = to_bf(v2);
  float s = v0 * v0 + v1 * v1 + v2 * v2;
  #pragma unroll
  for (int off = 32; off; off >>= 1) s += __shfl_xor(s, off);
  if (lane == 0) sq[row] = s;
  int b = blockIdx.x;
  if (b < 32)       posw[b * 256 + threadIdx.x] = 0ULL;
  else if (b < 64)  negw[(b - 32) * 256 + threadIdx.x] = ~0ULL;
  else if (b == 64 && threadIdx.x < 4) ((unsigned*)accum)[threadIdx.x] = 0u;
}

// ---------------- hard mining (j=M from LDS, i=N in regs) + fused CE ----------------
// wave w owns j-band [w*32, w*32+32) of each TJ=128 tile, and all TI=64 i-cols.
// Staging: global_load_lds (linear LDS dest) with inverse-swizzled global source;
// fragment ds_reads apply the same XOR swizzle.
// launch_bounds(256,2): cap = 256 regs — allocator must NOT spill. Actual
// allocation (arch ~128 + 32 acc) decides occupancy; if <=168 total we get
// 3 waves/SIMD for free. (256,3) pinned the cap at 170 and caused 80 MB of
// scratch spill traffic — the round-1/2 regression.
__global__ __launch_bounds__(256, 2) void mine_kernel(
    const unsigned short* __restrict__ ebf, const int* __restrict__ tgt,
    const float* __restrict__ sq, const float* __restrict__ logits,
    unsigned long long* __restrict__ posw, unsigned long long* __restrict__ negw,
    float* __restrict__ accum) {
  __shared__ unsigned short lds_b[TJ * (RB / 2)];   // 49152 B, linear rows of 384 B
  __shared__ int   lds_t[TJ];
  __shared__ float lds_s[TJ];
  __shared__ unsigned long long pmrg[TI];
  __shared__ unsigned long long nmrg[TI];
  __shared__ float ce_part[4];

  const int tid  = threadIdx.x;
  const int w    = tid >> 6;      // wave id = j band within tile
  const int lane = tid & 63;
  const int n5   = lane & 31;
  const int h    = lane >> 5;
  const int i0 = blockIdx.x * TI;
  const int jb = blockIdx.y * JLEN;

  char* ldsc = (char*)lds_b;

  if (tid < TI) { pmrg[tid] = 0ULL; nmrg[tid] = ~0ULL; }

  // ---- stage this block's 64 i-rows: async HBM->LDS, swizzled source ----
  {
    const char* src = (const char*)(ebf + (size_t)i0 * D_DIM);
    #pragma unroll
    for (int t = 0; t < 6; ++t) {           // 64 rows * 24 chunks = 1536 = 6*256
      int c  = t * 256 + tid;
      int r  = c / 24;
      int cb = (c - r * 24) * 16;
      gll16(src + r * RB + (cb ^ ((r & 7) << 4)),
            ldsc + (t * 256 + (tid & ~63)) * 16);
    }
  }
  __syncthreads();
  v8s bfrag[2][12];
  #pragma unroll
  for (int tb = 0; tb < 2; ++tb)
    #pragma unroll
    for (int kc = 0; kc < 12; ++kc)
      bfrag[tb][kc] = *(const v8s*)(ldsc + swzb(tb * 32 + n5, kc * 32 + h * 16));

  int my_t[2];
  #pragma unroll
  for (int tb = 0; tb < 2; ++tb) my_t[tb] = tgt[i0 + tb * 32 + n5];

  float    pv[2] = {-3.4e38f, -3.4e38f}, nv[2] = {3.4e38f, 3.4e38f};
  unsigned pi_[2] = {0u, 0u}, ni_[2] = {0xFFFFFFFFu, 0xFFFFFFFFu};

  for (int j0 = jb; j0 < jb + JLEN; j0 += TJ) {
    __syncthreads();
    // stage j-rows (M side): async HBM->LDS, swizzled source
    {
      const char* src = (const char*)(ebf + (size_t)j0 * D_DIM);
      #pragma unroll
      for (int t = 0; t < 12; ++t) {        // 128 rows * 24 chunks = 3072 = 12*256
        int c  = t * 256 + tid;
        int r  = c / 24;
        int cb = (c - r * 24) * 16;
        gll16(src + r * RB + (cb ^ ((r & 7) << 4)),
              ldsc + (t * 256 + (tid & ~63)) * 16);
      }
    }
    if (tid < TJ) { lds_t[tid] = tgt[j0 + tid]; lds_s[tid] = sq[j0 + tid]; }
    __syncthreads();   // drains vmcnt: all LDS writes landed

    v16f acc[2];
    #pragma unroll
    for (int tb = 0; tb < 2; ++tb)
      #pragma unroll
      for (int r = 0; r < 16; ++r) acc[tb][r] = 0.f;

    #pragma unroll
    for (int kc = 0; kc < 12; ++kc) {
      v8s afr = *(const v8s*)(ldsc + swzb(w * 32 + n5, kc * 32 + h * 16));
      acc[0] = __builtin_amdgcn_mfma_f32_32x32x16_bf16(afr, bfrag[0][kc], acc[0], 0, 0, 0);
      acc[1] = __builtin_amdgcn_mfma_f32_32x32x16_bf16(afr, bfrag[1][kc], acc[1], 0, 0, 0);
    }

    // epilogue: rows decode as j = w*32 + q + 8p + 4h ; col = i = tb*32 + (lane&31)
    #pragma unroll
    for (int p = 0; p < 4; ++p) {
      int jb4 = w * 32 + p * 8 + h * 4;
      float4 s4 = *(const float4*)&lds_s[jb4];   // broadcast (2 uniq addrs/wave)
      int4   t4 = *(const int4*)&lds_t[jb4];
      #pragma unroll
      for (int q = 0; q < 4; ++q) {
        float sv = (q == 0) ? s4.x : (q == 1) ? s4.y : (q == 2) ? s4.z : s4.w;
        int   tv = (q == 0) ? t4.x : (q == 1) ? t4.y : (q == 2) ? t4.z : t4.w;
        unsigned jg = (unsigned)(j0 + jb4 + q);
        #pragma unroll
        for (int tb = 0; tb < 2; ++tb) {
          float val = fmaf(acc[tb][p * 4 + q], -2.0f, sv);
          bool same = (tv == my_t[tb]);
          float vp = same ? val : -3.4e38f;
          float vn = same ? 3.4e38f : val;
          if (vp > pv[tb]) { pv[tb] = vp; pi_[tb] = jg; }
          if (vn < nv[tb]) { nv[tb] = vn; ni_[tb] = jg; }
        }
      }
    }
  }

  // ---- merge: h-partner lanes (shfl), then 4 waves via LDS atomics, then global ----
  #pragma unroll
  for (int tb = 0; tb < 2; ++tb) {
    unsigned long long pk =
        ((unsigned long long)fkey(pv[tb]) << 32) | (unsigned long long)(unsigned)(~pi_[tb]);
    unsigned long long nk =
        ((unsigned long long)fkey(nv[tb]) << 32) | (unsigned long long)ni_[tb];
    unsigned long long po = __shfl_xor(pk, 32);
    unsigned long long no = __shfl_xor(nk, 32);
    pk = pk > po ? pk : po;
    nk = nk < no ? nk : no;
    if (h == 0) {
      atomicMax(&pmrg[tb * 32 + n5], pk);
      atomicMin(&nmrg[tb * 32 + n5], nk);
    }
  }
  __syncthreads();
  if (tid < TI) {
    atomicMax(&posw[i0 + tid], pmrg[tid]);
    atomicMin(&negw[i0 + tid], nmrg[tid]);
  }

  // ---- fused cross-entropy: this block handles 4 logits rows (1 per wave) ----
  {
    int row = (blockIdx.y * 128 + blockIdx.x) * 4 + w;
    const float* lp = logits + (size_t)row * C_CLS;
    float4 x[4];
    #pragma unroll
    for (int t = 0; t < 4; ++t) x[t] = *(const float4*)(lp + lane * 4 + 256 * t);
    float m = -3.4e38f;
    #pragma unroll
    for (int t = 0; t < 4; ++t)
      m = fmaxf(m, fmaxf(fmaxf(x[t].x, x[t].y), fmaxf(x[t].z, x[t].w)));
    #pragma unroll
    for (int off = 32; off; off >>= 1) m = fmaxf(m, __shfl_xor(m, off));
    float s = 0.f;
    #pragma unroll
    for (int t = 0; t < 4; ++t)
      s += __expf(x[t].x - m) + __expf(x[t].y - m) +
           __expf(x[t].z - m) + __expf(x[t].w - m);
    #pragma unroll
    for (int off = 32; off; off >>= 1) s += __shfl_xor(s, off);
    if (lane == 0) ce_part[w] = m + __logf(s) - lp[tgt[row]];
  }
  __syncthreads();
  if (tid == 0)
    atomicAdd(&accum[0], ce_part[0] + ce_part[1] + ce_part[2] + ce_part[3]);
}

// ---------------- triplet loss on mined indices + last-block finalize ----------------
__global__ __launch_bounds__(1024) void trip_fin_kernel(
    const float* __restrict__ e,
    const unsigned long long* __restrict__ posw,
    const unsigned long long* __restrict__ negw,
    float* __restrict__ accum, float* __restrict__ out) {
  __shared__ float ssum[16];
  __shared__ float scnt[16];
  int w = threadIdx.x >> 6, lane = threadIdx.x & 63;
  int i = blockIdx.x * 16 + w;
  unsigned long long pp = posw[i], np = negw[i];
  unsigned pidx = ~(unsigned)pp;
  unsigned nidx = (unsigned)np;
  float res = 0.f, c = 0.f;
  // pidx == i means self won the argmax => no real positive => invalid row
  if (pp != 0ULL && np != ~0ULL && pidx != (unsigned)i) {
    const float* pa = e + (size_t)i * D_DIM;
    const float* pb = e + (size_t)pidx * D_DIM;
    const float* pc = e + (size_t)nidx * D_DIM;
    float dap = 0.f, dan = 0.f;
    #pragma unroll
    for (int t = 0; t < 3; ++t) {
      int k = lane + 64 * t;
      float av = pa[k];
      float d1 = av - pb[k] + EPS_T;
      float d2 = av - pc[k] + EPS_T;
      dap += d1 * d1;
      dan += d2 * d2;
    }
    #pragma unroll
    for (int off = 32; off; off >>= 1) {
      dap += __shfl_xor(dap, off);
      dan += __shfl_xor(dan, off);
    }
    res = fmaxf(sqrtf(dap) - sqrtf(dan) + MARGIN, 0.f);
    c = 1.f;
  }
  if (lane == 0) { ssum[w] = res; scnt[w] = c; }
  __syncthreads();
  if (threadIdx.x == 0) {
    float a = 0.f, b = 0.f;
    #pragma unroll
    for (int k = 0; k < 16; ++k) { a += ssum[k]; b += scnt[k]; }
    atomicAdd(&accum[1], a);
    atomicAdd(&accum[2], b);
    __threadfence();
    unsigned old = atomicAdd((unsigned*)&accum[3], 1u);
    if (old == 511u) {
      __threadfence();
      float cls = atomicAdd(&accum[0], 0.f);   // coherent reads via atomics
      float ts  = atomicAdd(&accum[1], 0.f);
      float tc  = atomicAdd(&accum[2], 0.f);
      float trip = (tc > 0.f) ? ts / fmaxf(tc, 1.f) : 0.f;
      out[0] = cls / (float)B_N + trip;
    }
  }
}

extern "C" void kernel_launch(void* const* d_in, const int* in_sizes, int n_in,
                              void* d_out, int out_size, void* d_ws, size_t ws_size,
                              hipStream_t stream) {
  const float* emb    = (const float*)d_in[0];
  const float* logits = (const float*)d_in[1];
  const int*   tgt    = (const int*)d_in[2];
  float* out = (float*)d_out;

  char* ws = (char*)d_ws;
  unsigned short* ebf = (unsigned short*)ws;                          // 3,145,728 B
  unsigned long long* posw = (unsigned long long*)(ws + 3145728);     // 65536 B
  unsigned long long* negw = (unsigned long long*)(ws + 3145728 + 65536);
  float* sq    = (float*)(ws + 3145728 + 131072);                     // 32768 B
  float* accum = (float*)(ws + 3145728 + 163840);                     // 16 B: cls,tsum,tcnt,counter

  prep_kernel<<<2048, 256, 0, stream>>>(emb, ebf, sq, posw, negw, accum);
  mine_kernel<<<dim3(B_N / TI, JSPLIT), 256, 0, stream>>>(ebf, tgt, sq, logits, posw, negw, accum);
  trip_fin_kernel<<<512, 1024, 0, stream>>>(emb, posw, negw, accum, out);
}

// Round 5
// 150.749 us; speedup vs baseline: 1.4320x; 1.0564x over previous
//
#include <hip/hip_runtime.h>
#include <math.h>

#define B_N    8192
#define D_DIM  192
#define C_CLS  1024
#define MARGIN 0.2f
#define EPS_T  1e-6f

#define TI     128
#define TJ     128
#define JSPLIT 4
#define JLEN   (B_N / JSPLIT)   // 2048
#define NT     (JLEN / TJ)      // 16 tiles per block
#define RB     384              // bytes per LDS row (linear 192 bf16, required by global_load_lds)

typedef short v8s  __attribute__((ext_vector_type(8)));
typedef float v16f __attribute__((ext_vector_type(16)));

typedef __attribute__((address_space(3))) unsigned int       lds_u32;
typedef __attribute__((address_space(1))) const unsigned int glb_u32;

__device__ __forceinline__ void gll16(const void* g, void* l) {
  __builtin_amdgcn_global_load_lds((glb_u32*)g, (lds_u32*)l, 16, 0, 0);
}

// XOR swizzle: physical byte for logical (row r, col-byte cb). Bijective involution
// within each 384-B row; 16B-aligned cb stays 16B-aligned. (r&7) is the max safe
// XOR: 16B-slot indices 0..23 are closed under ^7 within 8-slot groups.
__device__ __forceinline__ int swzb(int r, int cb) {
  return r * RB + (cb ^ ((r & 7) << 4));
}

// stage one 128-row x 384-B tile: 3072 16-B chunks, 6 per thread (512 threads).
// LDS dest is wave-uniform base + lane*16 (global_load_lds rule); the global
// source carries the inverse swizzle so swizzled ds_reads see linear data.
__device__ __forceinline__ void stage_tile(char* dst, const char* src, int tid) {
  #pragma unroll
  for (int k = 0; k < 6; ++k) {
    int c  = k * 512 + tid;
    int r  = c / 24;
    int cb = (c - r * 24) * 16;
    gll16(src + r * RB + (cb ^ ((r & 7) << 4)),
          dst + (k * 512 + (tid & ~63)) * 16);
  }
}

__device__ __forceinline__ unsigned fkey(float f) {
  unsigned u = __float_as_uint(f);
  return (u & 0x80000000u) ? ~u : (u | 0x80000000u);
}

__device__ __forceinline__ unsigned short to_bf(float x) {
  unsigned u = __float_as_uint(x);
  u += 0x7fffu + ((u >> 16) & 1u);
  return (unsigned short)(u >> 16);
}

// ---------------- prep: cvt fp32->bf16, sq = ||e||^2, init ws ----------------
__global__ __launch_bounds__(256) void prep_kernel(
    const float* __restrict__ e, unsigned short* __restrict__ ebf,
    float* __restrict__ sq,
    unsigned long long* __restrict__ posw, unsigned long long* __restrict__ negw,
    float* __restrict__ accum) {
  int w = threadIdx.x >> 6, lane = threadIdx.x & 63;
  int row = blockIdx.x * 4 + w;
  const float* p = e + (size_t)row * D_DIM;
  float v0 = p[lane], v1 = p[lane + 64], v2 = p[lane + 128];
  unsigned short* q = ebf + (size_t)row * D_DIM;
  q[lane] = to_bf(v0); q[lane + 64] = to_bf(v1); q[lane + 128] = to_bf(v2);
  float s = v0 * v0 + v1 * v1 + v2 * v2;
  #pragma unroll
  for (int off = 32; off; off >>= 1) s += __shfl_xor(s, off);
  if (lane == 0) sq[row] = s;
  int b = blockIdx.x;
  if (b < 32)       posw[b * 256 + threadIdx.x] = 0ULL;
  else if (b < 64)  negw[(b - 32) * 256 + threadIdx.x] = ~0ULL;
  else if (b == 64 && threadIdx.x < 4) ((unsigned*)accum)[threadIdx.x] = 0u;
}

// ---------------- hard mining: 2-phase double-buffered pipeline + fused CE ----------------
// 512 threads = 8 waves: wave w -> j-band wj = w&3 (32 rows of the TJ=128 tile),
// i-half wi = w>>2 (64 of the TI=128 i-cols). bfrag resident (96 VGPR), acc[2] (32).
// Per tile: issue next tile's global_load_lds into buf[cur^1] FIRST, then compute
// tile t from buf[cur]; single barrier per tile. The vmcnt(0) drain at the barrier
// is cheap because the loads had the entire compute phase to land (T3-minimum).
__global__ __launch_bounds__(512, 1) void mine_kernel(
    const unsigned short* __restrict__ ebf, const int* __restrict__ tgt,
    const float* __restrict__ sq, const float* __restrict__ logits,
    unsigned long long* __restrict__ posw, unsigned long long* __restrict__ negw,
    float* __restrict__ accum) {
  __shared__ unsigned short buf[2][TJ * (RB / 2)];   // 2 x 49152 B
  __shared__ int   lds_t[2][TJ];
  __shared__ float lds_s[2][TJ];
  __shared__ unsigned long long pmrg[TI];
  __shared__ unsigned long long nmrg[TI];
  __shared__ float ce_part[8];

  const int tid  = threadIdx.x;
  const int w    = tid >> 6;
  const int lane = tid & 63;
  const int n5   = lane & 31;
  const int h    = lane >> 5;
  const int wj   = w & 3;      // j-band within tile
  const int wi   = w >> 2;     // i-half
  const int i0 = blockIdx.x * TI;
  const int jb = blockIdx.y * JLEN;

  char* bufA = (char*)buf[0];
  char* bufB = (char*)buf[1];

  if (tid < TI) { pmrg[tid] = 0ULL; nmrg[tid] = ~0ULL; }

  // ---- prologue: i-tile -> bufB, j-tile 0 -> bufA (both async) ----
  stage_tile(bufB, (const char*)(ebf + (size_t)i0 * D_DIM), tid);
  stage_tile(bufA, (const char*)(ebf + (size_t)jb * D_DIM), tid);
  if (tid < TJ) { lds_t[0][tid] = tgt[jb + tid]; lds_s[0][tid] = sq[jb + tid]; }
  __syncthreads();   // vmcnt(0): both tiles landed

  v8s bfrag[2][12];
  #pragma unroll
  for (int tb = 0; tb < 2; ++tb)
    #pragma unroll
    for (int kc = 0; kc < 12; ++kc)
      bfrag[tb][kc] = *(const v8s*)(bufB + swzb(wi * 64 + tb * 32 + n5, kc * 32 + h * 16));

  int my_t[2];
  #pragma unroll
  for (int tb = 0; tb < 2; ++tb) my_t[tb] = tgt[i0 + wi * 64 + tb * 32 + n5];

  __syncthreads();   // all bfrag reads done before loop overwrites bufB

  float    pv[2] = {-3.4e38f, -3.4e38f}, nv[2] = {3.4e38f, 3.4e38f};
  unsigned pi_[2] = {0u, 0u}, ni_[2] = {0xFFFFFFFFu, 0xFFFFFFFFu};

  for (int t = 0; t < NT; ++t) {
    const int cur = t & 1;
    char* cbuf = (char*)buf[cur];

    // ---- phase 1: issue next tile's staging (async, other buffer) ----
    if (t + 1 < NT) {
      int jn = jb + (t + 1) * TJ;
      stage_tile((char*)buf[cur ^ 1], (const char*)(ebf + (size_t)jn * D_DIM), tid);
      if (tid < TJ) { lds_t[cur ^ 1][tid] = tgt[jn + tid]; lds_s[cur ^ 1][tid] = sq[jn + tid]; }
    }

    // ---- phase 2: compute tile t from buf[cur] ----
    v16f acc[2];
    #pragma unroll
    for (int tb = 0; tb < 2; ++tb)
      #pragma unroll
      for (int r = 0; r < 16; ++r) acc[tb][r] = 0.f;

    #pragma unroll
    for (int kc = 0; kc < 12; ++kc) {
      v8s afr = *(const v8s*)(cbuf + swzb(wj * 32 + n5, kc * 32 + h * 16));
      acc[0] = __builtin_amdgcn_mfma_f32_32x32x16_bf16(afr, bfrag[0][kc], acc[0], 0, 0, 0);
      acc[1] = __builtin_amdgcn_mfma_f32_32x32x16_bf16(afr, bfrag[1][kc], acc[1], 0, 0, 0);
    }

    // epilogue: j = wj*32 + q + 8p + 4h ; i = wi*64 + tb*32 + (lane&31)
    const int j0 = jb + t * TJ;
    #pragma unroll
    for (int p = 0; p < 4; ++p) {
      int jb4 = wj * 32 + p * 8 + h * 4;
      float4 s4 = *(const float4*)&lds_s[cur][jb4];
      int4   t4 = *(const int4*)&lds_t[cur][jb4];
      #pragma unroll
      for (int q = 0; q < 4; ++q) {
        float sv = (q == 0) ? s4.x : (q == 1) ? s4.y : (q == 2) ? s4.z : s4.w;
        int   tv = (q == 0) ? t4.x : (q == 1) ? t4.y : (q == 2) ? t4.z : t4.w;
        unsigned jg = (unsigned)(j0 + jb4 + q);
        #pragma unroll
        for (int tb = 0; tb < 2; ++tb) {
          float val = fmaf(acc[tb][p * 4 + q], -2.0f, sv);
          bool same = (tv == my_t[tb]);
          float vp = same ? val : -3.4e38f;
          float vn = same ? 3.4e38f : val;
          if (vp > pv[tb]) { pv[tb] = vp; pi_[tb] = jg; }
          if (vn < nv[tb]) { nv[tb] = vn; ni_[tb] = jg; }
        }
      }
    }

    __syncthreads();   // next buffer filled (loads landed during compute); cur reads done
  }

  // ---- merge: h-partner lanes (shfl), then 8 waves via LDS atomics, then global ----
  #pragma unroll
  for (int tb = 0; tb < 2; ++tb) {
    unsigned long long pk =
        ((unsigned long long)fkey(pv[tb]) << 32) | (unsigned long long)(unsigned)(~pi_[tb]);
    unsigned long long nk =
        ((unsigned long long)fkey(nv[tb]) << 32) | (unsigned long long)ni_[tb];
    unsigned long long po = __shfl_xor(pk, 32);
    unsigned long long no = __shfl_xor(nk, 32);
    pk = pk > po ? pk : po;
    nk = nk < no ? nk : no;
    if (h == 0) {
      atomicMax(&pmrg[wi * 64 + tb * 32 + n5], pk);
      atomicMin(&nmrg[wi * 64 + tb * 32 + n5], nk);
    }
  }
  __syncthreads();
  if (tid < TI) {
    atomicMax(&posw[i0 + tid], pmrg[tid]);
    atomicMin(&negw[i0 + tid], nmrg[tid]);
  }

  // ---- fused cross-entropy: 32 logits rows per block (4 per wave) ----
  {
    int blin = blockIdx.y * 64 + blockIdx.x;   // 0..255
    float ce_acc = 0.f;
    #pragma unroll
    for (int it = 0; it < 4; ++it) {
      int row = blin * 32 + w * 4 + it;
      const float* lp = logits + (size_t)row * C_CLS;
      float4 x[4];
      #pragma unroll
      for (int u = 0; u < 4; ++u) x[u] = *(const float4*)(lp + lane * 4 + 256 * u);
      float m = -3.4e38f;
      #pragma unroll
      for (int u = 0; u < 4; ++u)
        m = fmaxf(m, fmaxf(fmaxf(x[u].x, x[u].y), fmaxf(x[u].z, x[u].w)));
      #pragma unroll
      for (int off = 32; off; off >>= 1) m = fmaxf(m, __shfl_xor(m, off));
      float s = 0.f;
      #pragma unroll
      for (int u = 0; u < 4; ++u)
        s += __expf(x[u].x - m) + __expf(x[u].y - m) +
             __expf(x[u].z - m) + __expf(x[u].w - m);
      #pragma unroll
      for (int off = 32; off; off >>= 1) s += __shfl_xor(s, off);
      if (lane == 0) ce_acc += m + __logf(s) - lp[tgt[row]];
    }
    if (lane == 0) ce_part[w] = ce_acc;
  }
  __syncthreads();
  if (tid == 0) {
    float a = 0.f;
    #pragma unroll
    for (int k = 0; k < 8; ++k) a += ce_part[k];
    atomicAdd(&accum[0], a);
  }
}

// ---------------- triplet loss on mined indices + last-block finalize ----------------
__global__ __launch_bounds__(1024) void trip_fin_kernel(
    const float* __restrict__ e,
    const unsigned long long* __restrict__ posw,
    const unsigned long long* __restrict__ negw,
    float* __restrict__ accum, float* __restrict__ out) {
  __shared__ float ssum[16];
  __shared__ float scnt[16];
  int w = threadIdx.x >> 6, lane = threadIdx.x & 63;
  int i = blockIdx.x * 16 + w;
  unsigned long long pp = posw[i], np = negw[i];
  unsigned pidx = ~(unsigned)pp;
  unsigned nidx = (unsigned)np;
  float res = 0.f, c = 0.f;
  // pidx == i means self won the argmax => no real positive => invalid row
  if (pp != 0ULL && np != ~0ULL && pidx != (unsigned)i) {
    const float* pa = e + (size_t)i * D_DIM;
    const float* pb = e + (size_t)pidx * D_DIM;
    const float* pc = e + (size_t)nidx * D_DIM;
    float dap = 0.f, dan = 0.f;
    #pragma unroll
    for (int t = 0; t < 3; ++t) {
      int k = lane + 64 * t;
      float av = pa[k];
      float d1 = av - pb[k] + EPS_T;
      float d2 = av - pc[k] + EPS_T;
      dap += d1 * d1;
      dan += d2 * d2;
    }
    #pragma unroll
    for (int off = 32; off; off >>= 1) {
      dap += __shfl_xor(dap, off);
      dan += __shfl_xor(dan, off);
    }
    res = fmaxf(sqrtf(dap) - sqrtf(dan) + MARGIN, 0.f);
    c = 1.f;
  }
  if (lane == 0) { ssum[w] = res; scnt[w] = c; }
  __syncthreads();
  if (threadIdx.x == 0) {
    float a = 0.f, b = 0.f;
    #pragma unroll
    for (int k = 0; k < 16; ++k) { a += ssum[k]; b += scnt[k]; }
    atomicAdd(&accum[1], a);
    atomicAdd(&accum[2], b);
    __threadfence();
    unsigned old = atomicAdd((unsigned*)&accum[3], 1u);
    if (old == 511u) {
      __threadfence();
      float cls = atomicAdd(&accum[0], 0.f);   // coherent reads via atomics
      float ts  = atomicAdd(&accum[1], 0.f);
      float tc  = atomicAdd(&accum[2], 0.f);
      float trip = (tc > 0.f) ? ts / fmaxf(tc, 1.f) : 0.f;
      out[0] = cls / (float)B_N + trip;
    }
  }
}

extern "C" void kernel_launch(void* const* d_in, const int* in_sizes, int n_in,
                              void* d_out, int out_size, void* d_ws, size_t ws_size,
                              hipStream_t stream) {
  const float* emb    = (const float*)d_in[0];
  const float* logits = (const float*)d_in[1];
  const int*   tgt    = (const int*)d_in[2];
  float* out = (float*)d_out;

  char* ws = (char*)d_ws;
  unsigned short* ebf = (unsigned short*)ws;                          // 3,145,728 B
  unsigned long long* posw = (unsigned long long*)(ws + 3145728);     // 65536 B
  unsigned long long* negw = (unsigned long long*)(ws + 3145728 + 65536);
  float* sq    = (float*)(ws + 3145728 + 131072);                     // 32768 B
  float* accum = (float*)(ws + 3145728 + 163840);                     // 16 B: cls,tsum,tcnt,counter

  prep_kernel<<<2048, 256, 0, stream>>>(emb, ebf, sq, posw, negw, accum);
  mine_kernel<<<dim3(B_N / TI, JSPLIT), 512, 0, stream>>>(ebf, tgt, sq, logits, posw, negw, accum);
  trip_fin_kernel<<<512, 1024, 0, stream>>>(emb, posw, negw, accum, out);
}